// Round 9
// baseline (715.929 us; speedup 1.0000x reference)
//
#include <hip/hip_runtime.h>
#include <hip/hip_bf16.h>

#define N_NODES 100000
#define N_EDGES 1600000
#define N_GRAPHS 1024
#define F_NODE 16
#define F_EDGE 8
#define F_GRAPH 10
#define HD 64
#define HD2 128
#define GEN_EPS 1e-7f
#define SCAN_NBLK ((N_NODES + 255) / 256)   // 391
#define EB_BLK ((N_EDGES + 255) / 256)      // 6250
#define EMB_BLK ((N_NODES * HD + 255) / 256) // 25000

typedef unsigned short u16;
typedef unsigned int u32;
typedef __attribute__((ext_vector_type(8))) short short8;
typedef __attribute__((ext_vector_type(4))) float floatx4;

__device__ __forceinline__ u16 f2bf(float x) {   // RNE bf16 (finite inputs)
    u32 u = __float_as_uint(x);
    return (u16)((u + 0x7FFFu + ((u >> 16) & 1u)) >> 16);
}
__device__ __forceinline__ float bf2f(u16 u) {
    return __uint_as_float(((u32)u) << 16);
}
__device__ __forceinline__ float u2f(unsigned int u) {
    return __uint_as_float(u);
}

// ---- Fused front-end: hist | node-embed | weight-prep (independent roles).
// hist blocks are atomic/memory-bound, embed compute-bound, prep tiny —
// merging overlaps them on one dispatch (saves serial time + 2 launches).
__global__ void __launch_bounds__(256) k_front(
        const int* __restrict__ dst, int* __restrict__ deg,
        int* __restrict__ rank,
        const float* __restrict__ x, const float* __restrict__ W,
        const float* __restrict__ b, float* __restrict__ h,
        u16* __restrict__ hb,
        const float* __restrict__ W1a, const float* __restrict__ W2a,
        const float* __restrict__ W1b, const float* __restrict__ W2b,
        const float* __restrict__ W1c, const float* __restrict__ W2c,
        u16* __restrict__ W1t, u16* __restrict__ W2t) {
    int bid = blockIdx.x;
    if (bid < EB_BLK) {                      // ---- hist role
        int e = bid * 256 + threadIdx.x;
        if (e < N_EDGES) rank[e] = atomicAdd(&deg[dst[e]], 1);
        return;
    }
    if (bid >= EB_BLK + EMB_BLK) {           // ---- prep role (192 blocks)
        int pb = bid - (EB_BLK + EMB_BLK);   // [0,192): 64 per layer
        int l = pb >> 6;
        int t = (pb & 63) * 256 + threadIdx.x;   // [0, 16384)
        const float* W1 = (l == 0) ? W1a : (l == 1) ? W1b : W1c;
        const float* W2 = (l == 0) ? W2a : (l == 1) ? W2b : W2c;
        if (t < HD * HD2) {                  // W1t[j*64+k] = bf16(W1[k*128+j])
            int j = t >> 6, k = t & 63;
            W1t[(size_t)l * HD * HD2 + t] = f2bf(W1[k * HD2 + j]);
        } else {                             // W2t[c*128+j] = bf16(W2[j*64+c])
            int u = t - HD * HD2;
            int c = u >> 7, j = u & 127;
            W2t[(size_t)l * HD * HD2 + u] = f2bf(W2[j * HD + c]);
        }
        return;
    }
    // ---- embed role
    __shared__ float sW[F_NODE * HD];
    __shared__ float sb[HD];
    for (int i = threadIdx.x; i < F_NODE * HD; i += 256) sW[i] = W[i];
    if (threadIdx.x < HD) sb[threadIdx.x] = b[threadIdx.x];
    __syncthreads();
    int t = (bid - EB_BLK) * 256 + threadIdx.x;
    if (t >= N_NODES * HD) return;
    int n = t >> 6, f = t & 63;
    const float* xr = x + (size_t)n * F_NODE;
    float acc = sb[f];
#pragma unroll
    for (int k = 0; k < F_NODE; k++) acc += xr[k] * sW[k * HD + f];
    h[t] = acc;
    hb[t] = f2bf(acc);
}

// ---- CSR scans ----
__global__ void __launch_bounds__(256) k_scan1(
        const int* __restrict__ deg, int* __restrict__ bsum) {
    __shared__ int red[256];
    int t = threadIdx.x;
    int g = blockIdx.x * 256 + t;
    red[t] = (g < N_NODES) ? deg[g] : 0;
    __syncthreads();
    for (int s = 128; s > 0; s >>= 1) {
        if (t < s) red[t] += red[t + s];
        __syncthreads();
    }
    if (t == 0) bsum[blockIdx.x] = red[0];
}

__global__ void __launch_bounds__(512) k_scan2(
        const int* __restrict__ bsum, int* __restrict__ bpre) {
    __shared__ int sh[512];
    int t = threadIdx.x;
    int v = (t < SCAN_NBLK) ? bsum[t] : 0;
    sh[t] = v;
    __syncthreads();
    for (int d = 1; d < 512; d <<= 1) {
        int u = (t >= d) ? sh[t - d] : 0;
        __syncthreads();
        sh[t] += u;
        __syncthreads();
    }
    if (t < SCAN_NBLK) bpre[t] = sh[t] - v;   // exclusive
}

__global__ void __launch_bounds__(256) k_scan3(
        const int* __restrict__ deg, const int* __restrict__ bpre,
        int* __restrict__ off) {
    __shared__ int sh[256];
    int t = threadIdx.x;
    int g = blockIdx.x * 256 + t;
    int v = (g < N_NODES) ? deg[g] : 0;
    sh[t] = v;
    __syncthreads();
    for (int d = 1; d < 256; d <<= 1) {
        int u = (t >= d) ? sh[t - d] : 0;
        __syncthreads();
        sh[t] += u;
        __syncthreads();
    }
    int incl = sh[t];
    int base = bpre[blockIdx.x];
    if (g < N_NODES) off[g] = base + incl - v;
    if (g == N_NODES - 1) off[N_NODES] = base + incl;
}

// Scatter edge attrs (verbatim) + separate srcs[] array.
__global__ void __launch_bounds__(256) k_scatter(
        const int* __restrict__ src, const int* __restrict__ dst,
        const int* __restrict__ rank, const int* __restrict__ off,
        const float* __restrict__ eattr,
        unsigned int* __restrict__ rec, int* __restrict__ srcs) {
    int e = blockIdx.x * 256 + threadIdx.x;
    if (e >= N_EDGES) return;
    const uint4* ap = reinterpret_cast<const uint4*>(eattr + (size_t)e * F_EDGE);
    uint4 a0 = ap[0], a1 = ap[1];           // coalesced 32B read
    int pos = off[dst[e]] + rank[e];
    uint4* op = reinterpret_cast<uint4*>(rec + (size_t)pos * 8);
    op[0] = a0;                              // one 32B sector
    op[1] = a1;
    srcs[pos] = src[e];
}

// ---- GENConv aggregation (r5 chunk-8 version, best measured) ----
// One wave per destination node (lane = feature), grid-stride persistent.
// rec attrs: per-lane coalesced VMEM load + LDS broadcast (keeps the
// 51.2MB/layer stream off the scalar K$ — r5's proven fix). srcs via
// uniform s_load; batched hb gathers; one-chunk software pipeline.
// Chunk width 8 (r8's 16 wasted gathers on low-degree nodes). VGPR<=64.
__global__ void __launch_bounds__(256) k_gen_agg(
        const float* __restrict__ h, const u16* __restrict__ hb,
        const int* __restrict__ off,
        const unsigned int* __restrict__ rec,
        const int* __restrict__ srcs,
        const float* __restrict__ eW, const float* __restrict__ eb,
        float* __restrict__ outb) {
    __shared__ float sAttr[4][64];          // per-wave chunk staging, 1KB
    int wid = threadIdx.x >> 6;
    int lane = threadIdx.x & 63;
    int f = lane;
    float w[F_EDGE];
#pragma unroll
    for (int k = 0; k < F_EDGE; k++) w[k] = eW[k * HD + f];
    float bfv = eb[f];
    int wave0 = blockIdx.x * 4 + wid;
    const int NW = gridDim.x * 4;
    for (int n0 = wave0; n0 < N_NODES; n0 += NW) {
        int n = __builtin_amdgcn_readfirstlane(n0);
        int beg = off[n], end = off[n + 1];
        size_t idx = (size_t)n * HD + f;
        float hroot = h[idx];                 // hoisted; overlaps edge loop
        float den = 0.f, nm = 0.f;
        if (beg < end) {
            int i = beg;
            float av = 0.f;
            if (beg + (lane >> 3) < end) av = u2f(rec[(size_t)beg * 8 + lane]);
            int s8[8];
#pragma unroll
            for (int u = 0; u < 8; u++) s8[u] = srcs[beg + u];
            while (true) {
                float hv[8];
#pragma unroll
                for (int u = 0; u < 8; u++)
                    hv[u] = bf2f(hb[(size_t)s8[u] * HD + f]);
                int inx = i + 8;
                bool more = inx < end;
                float avN = 0.f;
                int s8N[8];
                if (more) {
                    if (inx + (lane >> 3) < end)
                        avN = u2f(rec[(size_t)inx * 8 + lane]);
#pragma unroll
                    for (int u = 0; u < 8; u++) s8N[u] = srcs[inx + u];
                } else {
#pragma unroll
                    for (int u = 0; u < 8; u++) s8N[u] = 0;
                }
                sAttr[wid][lane] = av;        // same-wave stage, no barrier
#pragma unroll
                for (int u = 0; u < 8; u++) {
                    if (i + u < end) {        // uniform guard
                        const floatx4* A = reinterpret_cast<const floatx4*>(
                            &sAttr[wid][u * 8]);
                        floatx4 a0 = A[0], a1 = A[1];   // broadcast ds_read_b128
                        float ea = bfv + a0.x * w[0] + a0.y * w[1]
                                       + a0.z * w[2] + a0.w * w[3]
                                       + a1.x * w[4] + a1.y * w[5]
                                       + a1.z * w[6] + a1.w * w[7];
                        float r = fmaxf(hv[u] + ea, 0.f);
                        float ev = __expf(r);
                        den += ev;
                        nm += r * ev;
                    }
                }
                if (!more) break;
                i = inx;
                av = avN;
#pragma unroll
                for (int u = 0; u < 8; u++) s8[u] = s8N[u];
            }
        }
        float agg = (end > beg) ? (nm / fmaxf(den, 1e-16f) + GEN_EPS) : 0.f;
        outb[idx] = hroot + agg;
    }
}

// ---- MLP (MFMA) v2: weights from pre-transposed bf16 global (L2-resident).
// LDS = sHid only (17.4KB -> 3 blocks/CU); hid rows wave-private -> no
// barrier. Verified in r8 (absmax 0).
__global__ void __launch_bounds__(256) k_mlp(
        const float* __restrict__ inb,
        const u16* __restrict__ W1t, const float* __restrict__ b1,
        const u16* __restrict__ W2t, const float* __restrict__ b2,
        float* __restrict__ hout, u16* __restrict__ hbout) {
    __shared__ u16 sHid[64][HD2 + 8];   // [local n][j], 17.4 KB
    int tid = threadIdx.x;
    int wid = tid >> 6, lane = tid & 63;
    int quad = lane >> 4, lm = lane & 15;
    int n0 = blockIdx.x * 64 + wid * 16;
    if (n0 >= N_NODES) return;            // 100000 % 16 == 0: whole-tile guard
    int node = n0 + lm;
    short8 a[2];
    const float* ar = inb + (size_t)node * HD;
#pragma unroll
    for (int kk = 0; kk < 2; kk++) {
        const float4* p = reinterpret_cast<const float4*>(ar + kk * 32 + quad * 8);
        float4 v0 = p[0], v1 = p[1];
        short8 t;
        t[0] = (short)f2bf(v0.x); t[1] = (short)f2bf(v0.y);
        t[2] = (short)f2bf(v0.z); t[3] = (short)f2bf(v0.w);
        t[4] = (short)f2bf(v1.x); t[5] = (short)f2bf(v1.y);
        t[6] = (short)f2bf(v1.z); t[7] = (short)f2bf(v1.w);
        a[kk] = t;
    }
    // hid = relu(A @ W1 + b1): B-frags direct from global
#pragma unroll
    for (int jt = 0; jt < 8; jt++) {
        int jb = jt * 16;
        float bias = b1[jb + lm];
        floatx4 acc = {bias, bias, bias, bias};
#pragma unroll
        for (int kk = 0; kk < 2; kk++) {
            const short8* bp = reinterpret_cast<const short8*>(
                W1t + (size_t)(jb + lm) * HD + kk * 32 + quad * 8);
            acc = __builtin_amdgcn_mfma_f32_16x16x32_bf16(a[kk], *bp, acc, 0, 0, 0);
        }
#pragma unroll
        for (int r = 0; r < 4; r++) {
            int lr = wid * 16 + quad * 4 + r;
            sHid[lr][jb + lm] = f2bf(fmaxf(acc[r], 0.f));
        }
    }
    // out = relu(hid @ W2 + b2); hid rows wave-private -> no barrier
    short8 a2[4];
#pragma unroll
    for (int kk = 0; kk < 4; kk++)
        a2[kk] = *reinterpret_cast<const short8*>(
            &sHid[wid * 16 + lm][kk * 32 + quad * 8]);
#pragma unroll
    for (int ct = 0; ct < 4; ct++) {
        int cb = ct * 16;
        float bias = b2[cb + lm];
        floatx4 acc = {bias, bias, bias, bias};
#pragma unroll
        for (int kk = 0; kk < 4; kk++) {
            const short8* bp = reinterpret_cast<const short8*>(
                W2t + (size_t)(cb + lm) * HD2 + kk * 32 + quad * 8);
            acc = __builtin_amdgcn_mfma_f32_16x16x32_bf16(a2[kk], *bp, acc, 0, 0, 0);
        }
#pragma unroll
        for (int r = 0; r < 4; r++) {
            int orow = n0 + quad * 4 + r;
            float o = fmaxf(acc[r], 0.f);
            hout[(size_t)orow * HD + cb + lm] = o;
            hbout[(size_t)orow * HD + cb + lm] = f2bf(o);
        }
    }
}

// One wave per graph; range via inline binary search on sorted batch.
__global__ void __launch_bounds__(256) k_pool(
        const float* __restrict__ h, const int* __restrict__ batch,
        float* __restrict__ pooled) {
    int g = blockIdx.x * 4 + (threadIdx.x >> 6);
    if (g >= N_GRAPHS) return;
    int f = threadIdx.x & 63;
    int lo = 0, hi = N_NODES;
    while (lo < hi) {
        int mid = (lo + hi) >> 1;
        if (batch[mid] < g) lo = mid + 1; else hi = mid;
    }
    int b = lo;
    int lo2 = b, hi2 = N_NODES;
    while (lo2 < hi2) {
        int mid = (lo2 + hi2) >> 1;
        if (batch[mid] < g + 1) lo2 = mid + 1; else hi2 = mid;
    }
    int e = lo2;
    float s = 0.f;
    for (int n = b; n < e; n++) s += h[(size_t)n * HD + f];
    float cnt = fmaxf((float)(e - b), 1.f);
    pooled[(size_t)g * HD + f] = s / cnt;
}

__global__ void __launch_bounds__(64) k_head(
        const float* __restrict__ pooled, const float* __restrict__ gattr,
        const float* __restrict__ d1W, const float* __restrict__ d1b,
        const float* __restrict__ d2W, const float* __restrict__ d2b,
        const float* __restrict__ oW, const float* __restrict__ ob,
        float* __restrict__ out) {
    int g = blockIdx.x;
    __shared__ float si[HD + F_GRAPH];
    __shared__ float s1[32], s2[32];
    int t = threadIdx.x;
    if (t < HD) si[t] = pooled[(size_t)g * HD + t];
    if (t < F_GRAPH) si[HD + t] = gattr[(size_t)g * F_GRAPH + t];
    __syncthreads();
    if (t < 32) {
        float acc = d1b[t];
        for (int i = 0; i < HD + F_GRAPH; i++) acc += si[i] * d1W[i * 32 + t];
        s1[t] = fmaxf(acc, 0.f);
    }
    __syncthreads();
    if (t < 32) {
        float acc = d2b[t];
        for (int i = 0; i < 32; i++) acc += s1[i] * d2W[i * 32 + t];
        s2[t] = fmaxf(acc, 0.f);
    }
    __syncthreads();
    if (t == 0) {
        float acc = ob[0];
        for (int i = 0; i < 32; i++) acc += s2[i] * oW[i];
        out[g] = 1.f / (1.f + __expf(-acc));
    }
}

extern "C" void kernel_launch(void* const* d_in, const int* in_sizes, int n_in,
                              void* d_out, int out_size, void* d_ws, size_t ws_size,
                              hipStream_t stream) {
    const float* x     = (const float*)d_in[0];
    const float* eattr = (const float*)d_in[1];
    const float* gattr = (const float*)d_in[2];
    const int*   eidx  = (const int*)d_in[3];
    const int*   batch = (const int*)d_in[4];
    const float* nodeW = (const float*)d_in[5];
    const float* nodeb = (const float*)d_in[6];
    const float* edgeW = (const float*)d_in[7];
    const float* edgeb = (const float*)d_in[8];
    const float* cW1[3] = {(const float*)d_in[9],  (const float*)d_in[13], (const float*)d_in[17]};
    const float* cb1[3] = {(const float*)d_in[10], (const float*)d_in[14], (const float*)d_in[18]};
    const float* cW2[3] = {(const float*)d_in[11], (const float*)d_in[15], (const float*)d_in[19]};
    const float* cb2[3] = {(const float*)d_in[12], (const float*)d_in[16], (const float*)d_in[20]};
    const float* d1W = (const float*)d_in[21];
    const float* d1b = (const float*)d_in[22];
    const float* d2W = (const float*)d_in[23];
    const float* d2b = (const float*)d_in[24];
    const float* oW  = (const float*)d_in[25];
    const float* ob  = (const float*)d_in[26];

    const int* src = eidx;
    const int* dst = eidx + N_EDGES;

    // workspace layout (srcs padded +64 ints (zeroed), rec padded +8 records)
    char* p = (char*)d_ws;
    float* h      = (float*)p; p += (size_t)N_NODES * HD * 4;       // 25.6 MB
    float* outb   = (float*)p; p += (size_t)N_NODES * HD * 4;       // 25.6 MB
    int*   srcs   = (int*)p;   p += (size_t)(N_EDGES + 64) * 4;     // 6.4 MB + pad
    unsigned int* rec = (unsigned int*)p; p += (size_t)(N_EDGES + 8) * F_EDGE * 4; // 51.2 MB + pad
    u16*   hb     = (u16*)p;   p += (size_t)N_NODES * HD * 2;       // 12.8 MB
    u16*   W1t    = (u16*)p;   p += (size_t)3 * HD * HD2 * 2;       // 48 KB
    u16*   W2t    = (u16*)p;   p += (size_t)3 * HD * HD2 * 2;       // 48 KB
    float* pooled = (float*)p; p += (size_t)N_GRAPHS * HD * 4;
    int*   off    = (int*)p;   p += (size_t)(N_NODES + 1) * 4;
    int*   deg    = (int*)p;   p += (size_t)N_NODES * 4;
    int*   rank   = (int*)p;   p += (size_t)N_EDGES * 4;            // 6.4 MB
    int*   bsum   = (int*)p;   p += (size_t)(SCAN_NBLK + 1) * 4;
    int*   bpre   = (int*)p;   p += (size_t)(SCAN_NBLK + 1) * 4;

    const int NBM = (N_NODES + 63) / 64;   // 1563 MFMA blocks (64 nodes each)

    // fused front-end: hist + node-embed + weight-prep in one dispatch
    hipMemsetAsync(deg, 0, (size_t)N_NODES * 4, stream);
    hipMemsetAsync(srcs + N_EDGES, 0, 64 * sizeof(int), stream);   // valid pad
    k_front<<<EB_BLK + EMB_BLK + 192, 256, 0, stream>>>(
        dst, deg, rank, x, nodeW, nodeb, h, hb,
        cW1[0], cW2[0], cW1[1], cW2[1], cW1[2], cW2[2], W1t, W2t);
    k_scan1<<<SCAN_NBLK, 256, 0, stream>>>(deg, bsum);
    k_scan2<<<1, 512, 0, stream>>>(bsum, bpre);
    k_scan3<<<SCAN_NBLK, 256, 0, stream>>>(deg, bpre, off);
    k_scatter<<<EB_BLK, 256, 0, stream>>>(src, dst, rank, off, eattr, rec, srcs);

    for (int l = 0; l < 3; l++) {
        k_gen_agg<<<2048, 256, 0, stream>>>(
            h, hb, off, rec, srcs, edgeW, edgeb, outb);
        k_mlp<<<NBM, 256, 0, stream>>>(outb,
                                       W1t + (size_t)l * HD * HD2, cb1[l],
                                       W2t + (size_t)l * HD * HD2, cb2[l],
                                       h, hb);
    }

    k_pool<<<(N_GRAPHS + 3) / 4, 256, 0, stream>>>(h, batch, pooled);
    k_head<<<N_GRAPHS, 64, 0, stream>>>(pooled, gattr,
                                        d1W, d1b, d2W, d2b, oW, ob,
                                        (float*)d_out);
}

// Round 10
// 672.511 us; speedup vs baseline: 1.0646x; 1.0646x over previous
//
#include <hip/hip_runtime.h>
#include <hip/hip_bf16.h>

#define N_NODES 100000
#define N_EDGES 1600000
#define N_GRAPHS 1024
#define F_NODE 16
#define F_EDGE 8
#define F_GRAPH 10
#define HD 64
#define HD2 128
#define GEN_EPS 1e-7f
#define SCAN_NBLK ((N_NODES + 255) / 256)   // 391

typedef unsigned short u16;
typedef unsigned int u32;
typedef __attribute__((ext_vector_type(8))) short short8;
typedef __attribute__((ext_vector_type(4))) float floatx4;

__device__ __forceinline__ u16 f2bf(float x) {   // RNE bf16 (finite inputs)
    u32 u = __float_as_uint(x);
    return (u16)((u + 0x7FFFu + ((u >> 16) & 1u)) >> 16);
}
__device__ __forceinline__ float bf2f(u16 u) {
    return __uint_as_float(((u32)u) << 16);
}
__device__ __forceinline__ float u2f(unsigned int u) {
    return __uint_as_float(u);
}

// h[n][f] = node_b[f] + sum_k x[n][k]*node_W[k][f]; also emits bf16 mirror hb.
__global__ void __launch_bounds__(256) k_node_embed(
        const float* __restrict__ x, const float* __restrict__ W,
        const float* __restrict__ b, float* __restrict__ h,
        u16* __restrict__ hb) {
    __shared__ float sW[F_NODE * HD];
    __shared__ float sb[HD];
    for (int i = threadIdx.x; i < F_NODE * HD; i += 256) sW[i] = W[i];
    if (threadIdx.x < HD) sb[threadIdx.x] = b[threadIdx.x];
    __syncthreads();
    int t = blockIdx.x * 256 + threadIdx.x;
    if (t >= N_NODES * HD) return;
    int n = t >> 6, f = t & 63;
    const float* xr = x + (size_t)n * F_NODE;
    float acc = sb[f];
#pragma unroll
    for (int k = 0; k < F_NODE; k++) acc += xr[k] * sW[k * HD + f];
    h[t] = acc;
    hb[t] = f2bf(acc);
}

// ---- CSR build ----
__global__ void __launch_bounds__(256) k_hist(
        const int* __restrict__ dst, int* __restrict__ deg,
        int* __restrict__ rank) {
    int e = blockIdx.x * 256 + threadIdx.x;
    if (e >= N_EDGES) return;
    rank[e] = atomicAdd(&deg[dst[e]], 1);
}

__global__ void __launch_bounds__(256) k_scan1(
        const int* __restrict__ deg, int* __restrict__ bsum) {
    __shared__ int red[256];
    int t = threadIdx.x;
    int g = blockIdx.x * 256 + t;
    red[t] = (g < N_NODES) ? deg[g] : 0;
    __syncthreads();
    for (int s = 128; s > 0; s >>= 1) {
        if (t < s) red[t] += red[t + s];
        __syncthreads();
    }
    if (t == 0) bsum[blockIdx.x] = red[0];
}

__global__ void __launch_bounds__(512) k_scan2(
        const int* __restrict__ bsum, int* __restrict__ bpre) {
    __shared__ int sh[512];
    int t = threadIdx.x;
    int v = (t < SCAN_NBLK) ? bsum[t] : 0;
    sh[t] = v;
    __syncthreads();
    for (int d = 1; d < 512; d <<= 1) {
        int u = (t >= d) ? sh[t - d] : 0;
        __syncthreads();
        sh[t] += u;
        __syncthreads();
    }
    if (t < SCAN_NBLK) bpre[t] = sh[t] - v;   // exclusive
}

__global__ void __launch_bounds__(256) k_scan3(
        const int* __restrict__ deg, const int* __restrict__ bpre,
        int* __restrict__ off) {
    __shared__ int sh[256];
    int t = threadIdx.x;
    int g = blockIdx.x * 256 + t;
    int v = (g < N_NODES) ? deg[g] : 0;
    sh[t] = v;
    __syncthreads();
    for (int d = 1; d < 256; d <<= 1) {
        int u = (t >= d) ? sh[t - d] : 0;
        __syncthreads();
        sh[t] += u;
        __syncthreads();
    }
    int incl = sh[t];
    int base = bpre[blockIdx.x];
    if (g < N_NODES) off[g] = base + incl - v;
    if (g == N_NODES - 1) off[N_NODES] = base + incl;
}

// Scatter edge attrs (verbatim) + separate srcs[] array.
__global__ void __launch_bounds__(256) k_scatter(
        const int* __restrict__ src, const int* __restrict__ dst,
        const int* __restrict__ rank, const int* __restrict__ off,
        const float* __restrict__ eattr,
        unsigned int* __restrict__ rec, int* __restrict__ srcs) {
    int e = blockIdx.x * 256 + threadIdx.x;
    if (e >= N_EDGES) return;
    const uint4* ap = reinterpret_cast<const uint4*>(eattr + (size_t)e * F_EDGE);
    uint4 a0 = ap[0], a1 = ap[1];           // coalesced 32B read
    int pos = off[dst[e]] + rank[e];
    uint4* op = reinterpret_cast<uint4*>(rec + (size_t)pos * 8);
    op[0] = a0;                              // one 32B sector
    op[1] = a1;
    srcs[pos] = src[e];
}

// ---- GENConv aggregation (r5 structure, bf16 output) ----
// One wave per destination node (lane = feature), grid-stride persistent.
// rec attrs: per-lane coalesced VMEM load + LDS broadcast (keeps the
// 51.2MB/layer stream off the scalar K$ — r5's proven fix). srcs via
// uniform s_load; batched hb gathers; one-chunk software pipeline.
// Output written as bf16 ONLY: mlp rounds its A-frags to bf16 anyway, so
// fp32 outb was pure wasted traffic (25.6->12.8 MB write, same numerics).
__global__ void __launch_bounds__(256) k_gen_agg(
        const float* __restrict__ h, const u16* __restrict__ hb,
        const int* __restrict__ off,
        const unsigned int* __restrict__ rec,
        const int* __restrict__ srcs,
        const float* __restrict__ eW, const float* __restrict__ eb,
        u16* __restrict__ outbb) {
    __shared__ float sAttr[4][64];          // per-wave chunk staging, 1KB
    int wid = threadIdx.x >> 6;
    int lane = threadIdx.x & 63;
    int f = lane;
    float w[F_EDGE];
#pragma unroll
    for (int k = 0; k < F_EDGE; k++) w[k] = eW[k * HD + f];
    float bfv = eb[f];
    int wave0 = blockIdx.x * 4 + wid;
    const int NW = gridDim.x * 4;
    for (int n0 = wave0; n0 < N_NODES; n0 += NW) {
        int n = __builtin_amdgcn_readfirstlane(n0);
        int beg = off[n], end = off[n + 1];
        size_t idx = (size_t)n * HD + f;
        float hroot = h[idx];                 // hoisted; overlaps edge loop
        float den = 0.f, nm = 0.f;
        if (beg < end) {
            int i = beg;
            float av = 0.f;
            if (beg + (lane >> 3) < end) av = u2f(rec[(size_t)beg * 8 + lane]);
            int s8[8];
#pragma unroll
            for (int u = 0; u < 8; u++) s8[u] = srcs[beg + u];
            while (true) {
                float hv[8];
#pragma unroll
                for (int u = 0; u < 8; u++)
                    hv[u] = bf2f(hb[(size_t)s8[u] * HD + f]);
                int inx = i + 8;
                bool more = inx < end;
                float avN = 0.f;
                int s8N[8];
                if (more) {
                    if (inx + (lane >> 3) < end)
                        avN = u2f(rec[(size_t)inx * 8 + lane]);
#pragma unroll
                    for (int u = 0; u < 8; u++) s8N[u] = srcs[inx + u];
                } else {
#pragma unroll
                    for (int u = 0; u < 8; u++) s8N[u] = 0;
                }
                sAttr[wid][lane] = av;        // same-wave stage, no barrier
#pragma unroll
                for (int u = 0; u < 8; u++) {
                    if (i + u < end) {        // uniform guard
                        const floatx4* A = reinterpret_cast<const floatx4*>(
                            &sAttr[wid][u * 8]);
                        floatx4 a0 = A[0], a1 = A[1];   // broadcast ds_read_b128
                        float ea = bfv + a0.x * w[0] + a0.y * w[1]
                                       + a0.z * w[2] + a0.w * w[3]
                                       + a1.x * w[4] + a1.y * w[5]
                                       + a1.z * w[6] + a1.w * w[7];
                        float r = fmaxf(hv[u] + ea, 0.f);
                        float ev = __expf(r);
                        den += ev;
                        nm += r * ev;
                    }
                }
                if (!more) break;
                i = inx;
                av = avN;
#pragma unroll
                for (int u = 0; u < 8; u++) s8[u] = s8N[u];
            }
        }
        float agg = (end > beg) ? (nm / fmaxf(den, 1e-16f) + GEN_EPS) : 0.f;
        outbb[idx] = f2bf(hroot + agg);
    }
}

// ---- Fused MLP (MFMA), r5 structure with bf16 input: hid = relu(in@W1+b1)
// staged in LDS, then h' = relu(hid@W2+b2). A-frags are now direct short8
// loads (input already bf16) — deletes the f32 load + 16 f2bf per thread.
// Layouts identical to the verified kernels:
// A[m=lane&15][k=quad*8+j], B[n=lane&15][k=quad*8+j], D col=lane&15 row=quad*4+r.
__global__ void __launch_bounds__(256) k_mlp(
        const u16* __restrict__ inb,
        const float* __restrict__ W1, const float* __restrict__ b1,
        const float* __restrict__ W2, const float* __restrict__ b2,
        float* __restrict__ hout, u16* __restrict__ hbout) {
    __shared__ u16 wB1[HD2][HD + 8];    // [j][k], 18.4 KB
    __shared__ u16 wB2[HD][HD2 + 8];    // [c][j], 17.4 KB
    __shared__ u16 sHid[64][HD2 + 8];   // [local n][j], 17.4 KB
    __shared__ float sb1[HD2];
    __shared__ float sb2[HD];
    int tid = threadIdx.x;
    for (int i = tid; i < HD * HD2; i += 256) {
        int ff = i >> 7, j = i & 127;
        wB1[j][ff] = f2bf(W1[i]);
    }
    for (int i = tid; i < HD2 * HD; i += 256) {
        int j = i >> 6, c = i & 63;
        wB2[c][j] = f2bf(W2[i]);
    }
    if (tid < HD2) sb1[tid] = b1[tid];
    if (tid < HD) sb2[tid] = b2[tid];
    __syncthreads();
    int wid = tid >> 6, lane = tid & 63;
    int quad = lane >> 4, lm = lane & 15;
    int n0 = blockIdx.x * 64 + wid * 16;
    bool active = (n0 < N_NODES);         // 100000 % 16 == 0: whole-tile guard
    if (active) {
        int node = n0 + lm;
        short8 a[2];
        const u16* ar = inb + (size_t)node * HD;
#pragma unroll
        for (int kk = 0; kk < 2; kk++)
            a[kk] = *reinterpret_cast<const short8*>(ar + kk * 32 + quad * 8);
#pragma unroll
        for (int jt = 0; jt < 8; jt++) {
            int jb = jt * 16;
            float bias = sb1[jb + lm];
            floatx4 acc = {bias, bias, bias, bias};
#pragma unroll
            for (int kk = 0; kk < 2; kk++) {
                const short8* bp = reinterpret_cast<const short8*>(
                    &wB1[jb + lm][kk * 32 + quad * 8]);
                acc = __builtin_amdgcn_mfma_f32_16x16x32_bf16(a[kk], *bp, acc, 0, 0, 0);
            }
#pragma unroll
            for (int r = 0; r < 4; r++) {
                int lr = wid * 16 + quad * 4 + r;
                sHid[lr][jb + lm] = f2bf(fmaxf(acc[r], 0.f));
            }
        }
    }
    __syncthreads();
    if (active) {
        short8 a2[4];
#pragma unroll
        for (int kk = 0; kk < 4; kk++)
            a2[kk] = *reinterpret_cast<const short8*>(
                &sHid[wid * 16 + lm][kk * 32 + quad * 8]);
#pragma unroll
        for (int ct = 0; ct < 4; ct++) {
            int cb = ct * 16;
            float bias = sb2[cb + lm];
            floatx4 acc = {bias, bias, bias, bias};
#pragma unroll
            for (int kk = 0; kk < 4; kk++) {
                const short8* bp = reinterpret_cast<const short8*>(
                    &wB2[cb + lm][kk * 32 + quad * 8]);
                acc = __builtin_amdgcn_mfma_f32_16x16x32_bf16(a2[kk], *bp, acc, 0, 0, 0);
            }
#pragma unroll
            for (int r = 0; r < 4; r++) {
                int orow = n0 + quad * 4 + r;
                float o = fmaxf(acc[r], 0.f);
                hout[(size_t)orow * HD + cb + lm] = o;
                hbout[(size_t)orow * HD + cb + lm] = f2bf(o);
            }
        }
    }
}

// One wave per graph; range via inline binary search on sorted batch.
__global__ void __launch_bounds__(256) k_pool(
        const float* __restrict__ h, const int* __restrict__ batch,
        float* __restrict__ pooled) {
    int g = blockIdx.x * 4 + (threadIdx.x >> 6);
    if (g >= N_GRAPHS) return;
    int f = threadIdx.x & 63;
    int lo = 0, hi = N_NODES;
    while (lo < hi) {
        int mid = (lo + hi) >> 1;
        if (batch[mid] < g) lo = mid + 1; else hi = mid;
    }
    int b = lo;
    int lo2 = b, hi2 = N_NODES;
    while (lo2 < hi2) {
        int mid = (lo2 + hi2) >> 1;
        if (batch[mid] < g + 1) lo2 = mid + 1; else hi2 = mid;
    }
    int e = lo2;
    float s = 0.f;
    for (int n = b; n < e; n++) s += h[(size_t)n * HD + f];
    float cnt = fmaxf((float)(e - b), 1.f);
    pooled[(size_t)g * HD + f] = s / cnt;
}

__global__ void __launch_bounds__(64) k_head(
        const float* __restrict__ pooled, const float* __restrict__ gattr,
        const float* __restrict__ d1W, const float* __restrict__ d1b,
        const float* __restrict__ d2W, const float* __restrict__ d2b,
        const float* __restrict__ oW, const float* __restrict__ ob,
        float* __restrict__ out) {
    int g = blockIdx.x;
    __shared__ float si[HD + F_GRAPH];
    __shared__ float s1[32], s2[32];
    int t = threadIdx.x;
    if (t < HD) si[t] = pooled[(size_t)g * HD + t];
    if (t < F_GRAPH) si[HD + t] = gattr[(size_t)g * F_GRAPH + t];
    __syncthreads();
    if (t < 32) {
        float acc = d1b[t];
        for (int i = 0; i < HD + F_GRAPH; i++) acc += si[i] * d1W[i * 32 + t];
        s1[t] = fmaxf(acc, 0.f);
    }
    __syncthreads();
    if (t < 32) {
        float acc = d2b[t];
        for (int i = 0; i < 32; i++) acc += s1[i] * d2W[i * 32 + t];
        s2[t] = fmaxf(acc, 0.f);
    }
    __syncthreads();
    if (t == 0) {
        float acc = ob[0];
        for (int i = 0; i < 32; i++) acc += s2[i] * oW[i];
        out[g] = 1.f / (1.f + __expf(-acc));
    }
}

extern "C" void kernel_launch(void* const* d_in, const int* in_sizes, int n_in,
                              void* d_out, int out_size, void* d_ws, size_t ws_size,
                              hipStream_t stream) {
    const float* x     = (const float*)d_in[0];
    const float* eattr = (const float*)d_in[1];
    const float* gattr = (const float*)d_in[2];
    const int*   eidx  = (const int*)d_in[3];
    const int*   batch = (const int*)d_in[4];
    const float* nodeW = (const float*)d_in[5];
    const float* nodeb = (const float*)d_in[6];
    const float* edgeW = (const float*)d_in[7];
    const float* edgeb = (const float*)d_in[8];
    const float* cW1[3] = {(const float*)d_in[9],  (const float*)d_in[13], (const float*)d_in[17]};
    const float* cb1[3] = {(const float*)d_in[10], (const float*)d_in[14], (const float*)d_in[18]};
    const float* cW2[3] = {(const float*)d_in[11], (const float*)d_in[15], (const float*)d_in[19]};
    const float* cb2[3] = {(const float*)d_in[12], (const float*)d_in[16], (const float*)d_in[20]};
    const float* d1W = (const float*)d_in[21];
    const float* d1b = (const float*)d_in[22];
    const float* d2W = (const float*)d_in[23];
    const float* d2b = (const float*)d_in[24];
    const float* oW  = (const float*)d_in[25];
    const float* ob  = (const float*)d_in[26];

    const int* src = eidx;
    const int* dst = eidx + N_EDGES;

    // workspace layout (srcs padded +64 ints (zeroed), rec padded +8 records;
    // outbb is the bf16 agg->mlp interface, was fp32)
    char* p = (char*)d_ws;
    float* h      = (float*)p; p += (size_t)N_NODES * HD * 4;       // 25.6 MB
    u16*   outbb  = (u16*)p;   p += (size_t)N_NODES * HD * 2;       // 12.8 MB
    int*   srcs   = (int*)p;   p += (size_t)(N_EDGES + 64) * 4;     // 6.4 MB + pad
    unsigned int* rec = (unsigned int*)p; p += (size_t)(N_EDGES + 8) * F_EDGE * 4; // 51.2 MB + pad
    u16*   hb     = (u16*)p;   p += (size_t)N_NODES * HD * 2;       // 12.8 MB
    float* pooled = (float*)p; p += (size_t)N_GRAPHS * HD * 4;
    int*   off    = (int*)p;   p += (size_t)(N_NODES + 1) * 4;
    int*   deg    = (int*)p;   p += (size_t)N_NODES * 4;
    int*   rank   = (int*)p;   p += (size_t)N_EDGES * 4;            // 6.4 MB
    int*   bsum   = (int*)p;   p += (size_t)(SCAN_NBLK + 1) * 4;
    int*   bpre   = (int*)p;   p += (size_t)(SCAN_NBLK + 1) * 4;

    const int EB = (N_EDGES + 255) / 256;
    const int NBM = (N_NODES + 63) / 64;   // 1563 MFMA blocks (64 nodes each)

    k_node_embed<<<(N_NODES * HD + 255) / 256, 256, 0, stream>>>(x, nodeW, nodeb, h, hb);

    // CSR build (atomic-free scatter via hist-captured ranks)
    hipMemsetAsync(deg, 0, (size_t)N_NODES * 4, stream);
    hipMemsetAsync(srcs + N_EDGES, 0, 64 * sizeof(int), stream);   // valid pad
    k_hist<<<EB, 256, 0, stream>>>(dst, deg, rank);
    k_scan1<<<SCAN_NBLK, 256, 0, stream>>>(deg, bsum);
    k_scan2<<<1, 512, 0, stream>>>(bsum, bpre);
    k_scan3<<<SCAN_NBLK, 256, 0, stream>>>(deg, bpre, off);
    k_scatter<<<EB, 256, 0, stream>>>(src, dst, rank, off, eattr, rec, srcs);

    for (int l = 0; l < 3; l++) {
        k_gen_agg<<<2048, 256, 0, stream>>>(
            h, hb, off, rec, srcs, edgeW, edgeb, outbb);
        k_mlp<<<NBM, 256, 0, stream>>>(outbb, cW1[l], cb1[l], cW2[l], cb2[l], h, hb);
    }

    k_pool<<<(N_GRAPHS + 3) / 4, 256, 0, stream>>>(h, batch, pooled);
    k_head<<<N_GRAPHS, 64, 0, stream>>>(pooled, gattr,
                                        d1W, d1b, d2W, d2b, oW, ob,
                                        (float*)d_out);
}